// Round 1
// baseline (425.771 us; speedup 1.0000x reference)
//
#include <hip/hip_runtime.h>

typedef __bf16 bf16x8 __attribute__((ext_vector_type(8)));
typedef float f32x4 __attribute__((ext_vector_type(4)));
typedef unsigned short u16;
typedef u16 u16x4 __attribute__((ext_vector_type(4)));

__device__ __forceinline__ u16 f2bf(float f) {
  unsigned u = __builtin_bit_cast(unsigned, f);
  u += 0x7FFFu + ((u >> 16) & 1u);   // RNE
  return (u16)(u >> 16);
}

#define GLDS16(g, l) __builtin_amdgcn_global_load_lds(                     \
    (const __attribute__((address_space(1))) unsigned int*)(g),            \
    (__attribute__((address_space(3))) unsigned int*)(l), 16, 0, 0)

__device__ __forceinline__ f32x4 mfma16(bf16x8 a, bf16x8 b, f32x4 c) {
  return __builtin_amdgcn_mfma_f32_16x16x32_bf16(a, b, c, 0, 0, 0);
}

// ---------------- fp32 -> bf16 convert ----------------
__global__ void cvt_bf16(const float* __restrict__ src, u16* __restrict__ dst, int n4) {
  int idx = blockIdx.x * blockDim.x + threadIdx.x;
  int stride = gridDim.x * blockDim.x;
  for (int i = idx; i < n4; i += stride) {
    float4 v = ((const float4*)src)[i];
    u16x4 o = { f2bf(v.x), f2bf(v.y), f2bf(v.z), f2bf(v.w) };
    ((u16x4*)dst)[i] = o;
  }
}

// ---------------- GEMM: A[M,K] bf16 row-major, B[N,K] bf16 row-major (B^T) ----------------
// MODE 0: qkv projection -> q/k region stored to QK [4096][4096] bf16,
//         v region (cols >= 4096) stored transposed to VT [(b*16+h)*128+d][2048] bf16
// MODE 1: fp32 store to C [M][N]
template<int MODE>
__global__ __launch_bounds__(256, 2) void gemm_bt(
    const u16* __restrict__ A, const u16* __restrict__ B,
    void* __restrict__ C, u16* __restrict__ VT,
    int M, int N, int K) {
  __shared__ __align__(16) u16 As[128 * 32];
  __shared__ __align__(16) u16 Bs[128 * 32];
  const int t = threadIdx.x;
  const int lane = t & 63;
  const int w = t >> 6;
  const int wm = w >> 1, wn = w & 1;
  const int m0 = blockIdx.y * 128, n0 = blockIdx.x * 128;
  f32x4 acc[4][4] = {};

  const u16* ga = A + (size_t)(m0 + (t >> 2)) * K + (t & 3) * 8;
  const u16* gb = B + (size_t)(n0 + (t >> 2)) * K + (t & 3) * 8;
  u16* la = (u16*)As + t * 8;
  u16* lb = (u16*)Bs + t * 8;
  const size_t half = (size_t)64 * K;

  for (int k0 = 0; k0 < K; k0 += 32) {
    GLDS16(ga + k0, la);
    GLDS16(ga + half + k0, la + 2048);
    GLDS16(gb + k0, lb);
    GLDS16(gb + half + k0, lb + 2048);
    __syncthreads();
    const int ro = (lane & 15) * 32 + (lane >> 4) * 8;
    bf16x8 af[4], bfr[4];
#pragma unroll
    for (int i = 0; i < 4; ++i) af[i]  = *(const bf16x8*)&As[(wm * 64 + i * 16) * 32 + ro];
#pragma unroll
    for (int i = 0; i < 4; ++i) bfr[i] = *(const bf16x8*)&Bs[(wn * 64 + i * 16) * 32 + ro];
#pragma unroll
    for (int i = 0; i < 4; ++i)
#pragma unroll
      for (int j = 0; j < 4; ++j)
        acc[i][j] = mfma16(af[i], bfr[j], acc[i][j]);
    __syncthreads();
  }

  const int rbase = m0 + wm * 64 + ((lane >> 4) << 2);
  const int cbase = n0 + wn * 64 + (lane & 15);
#pragma unroll
  for (int i = 0; i < 4; ++i) {
#pragma unroll
    for (int j = 0; j < 4; ++j) {
      const int row0 = rbase + i * 16;
      const int col = cbase + j * 16;
      if (MODE == 0) {
        if (col < 4096) {
          u16* cq = (u16*)C;
#pragma unroll
          for (int jj = 0; jj < 4; ++jj)
            cq[(size_t)(row0 + jj) * 4096 + col] = f2bf(acc[i][j][jj]);
        } else {
          const int bb = row0 >> 11, s = row0 & 2047;
          u16x4 pk = { f2bf(acc[i][j][0]), f2bf(acc[i][j][1]),
                       f2bf(acc[i][j][2]), f2bf(acc[i][j][3]) };
          *(u16x4*)&VT[(size_t)(bb * 2048 + (col - 4096)) * 2048 + s] = pk;
        }
      } else {
        float* cf = (float*)C;
#pragma unroll
        for (int jj = 0; jj < 4; ++jj)
          cf[(size_t)(row0 + jj) * N + col] = acc[i][j][jj];
      }
    }
  }
}

// ---------------- flash attention ----------------
// qk: [B][2048][4096] bf16 (cols 0..2047 = Q head h at h*128, 2048..4095 = K)
// vt: [B*16][128][2048] bf16 (d-major, s-contiguous)
// aout: [B*2048][2048] bf16
__global__ __launch_bounds__(256, 2) void attn_fwd(
    const u16* __restrict__ qk, const u16* __restrict__ vt, u16* __restrict__ aout) {
  __shared__ __align__(16) u16 Pl[4][32 * 72];
  const int t = threadIdx.x, lane = t & 63, w = t >> 6;
  const int b = blockIdx.z, h = blockIdx.y;
  const int q0 = blockIdx.x * 128 + w * 32;
  const int l15 = lane & 15, lg = lane >> 4;

  const u16* qp = qk + (size_t)b * 2048 * 4096 + h * 128;
  const u16* kp = qp + 2048;
  const u16* vtp = vt + (size_t)(b * 16 + h) * 128 * 2048;
  u16* op = aout + (size_t)b * 2048 * 2048 + h * 128;

  // Q fragments hoisted (rows q0..q0+31, all of d=128)
  bf16x8 qf[2][4];
#pragma unroll
  for (int mi = 0; mi < 2; ++mi)
#pragma unroll
    for (int kd = 0; kd < 4; ++kd)
      qf[mi][kd] = *(const bf16x8*)&qp[(size_t)(q0 + mi * 16 + l15) * 4096 + kd * 32 + lg * 8];

  f32x4 o[2][8] = {};
  float mrow[2][4], lrow[2][4];
#pragma unroll
  for (int mi = 0; mi < 2; ++mi)
#pragma unroll
    for (int j = 0; j < 4; ++j) { mrow[mi][j] = -1e30f; lrow[mi][j] = 0.f; }

  const float c = 0.08838834764831845f * 1.4426950408889634f; // D^-0.5 * log2(e)
  u16* pw = &Pl[w][0];

#pragma unroll 1
  for (int kt = 0; kt < 2048; kt += 64) {
    // S = Q @ K^T for 64 keys
    f32x4 sf[2][4];
#pragma unroll
    for (int ni = 0; ni < 4; ++ni) {
      const u16* kr = &kp[(size_t)(kt + ni * 16 + l15) * 4096 + lg * 8];
      bf16x8 kf0 = *(const bf16x8*)(kr);
      bf16x8 kf1 = *(const bf16x8*)(kr + 32);
      bf16x8 kf2 = *(const bf16x8*)(kr + 64);
      bf16x8 kf3 = *(const bf16x8*)(kr + 96);
#pragma unroll
      for (int mi = 0; mi < 2; ++mi) {
        f32x4 s = {0.f, 0.f, 0.f, 0.f};
        s = mfma16(qf[mi][0], kf0, s);
        s = mfma16(qf[mi][1], kf1, s);
        s = mfma16(qf[mi][2], kf2, s);
        s = mfma16(qf[mi][3], kf3, s);
        sf[mi][ni] = s;
      }
    }
    // online softmax: row max
    float alpha[2][4], rs[2][4];
#pragma unroll
    for (int mi = 0; mi < 2; ++mi)
#pragma unroll
      for (int j = 0; j < 4; ++j) {
        float v = fmaxf(fmaxf(sf[mi][0][j], sf[mi][1][j]),
                        fmaxf(sf[mi][2][j], sf[mi][3][j])) * c;
#pragma unroll
        for (int d = 1; d < 16; d <<= 1) v = fmaxf(v, __shfl_xor(v, d));
        float mnew = fmaxf(mrow[mi][j], v);
        alpha[mi][j] = exp2f(mrow[mi][j] - mnew);
        mrow[mi][j] = mnew;
        rs[mi][j] = 0.f;
      }
    // P = exp2(S*c - m), write bf16 to padded LDS
#pragma unroll
    for (int mi = 0; mi < 2; ++mi)
#pragma unroll
      for (int ni = 0; ni < 4; ++ni)
#pragma unroll
        for (int j = 0; j < 4; ++j) {
          float p = exp2f(fmaf(sf[mi][ni][j], c, -mrow[mi][j]));
          rs[mi][j] += p;
          pw[(mi * 16 + lg * 4 + j) * 72 + ni * 16 + l15] = f2bf(p);
        }
    // row sum -> l update
#pragma unroll
    for (int mi = 0; mi < 2; ++mi)
#pragma unroll
      for (int j = 0; j < 4; ++j) {
        float v = rs[mi][j];
#pragma unroll
        for (int d = 1; d < 16; d <<= 1) v += __shfl_xor(v, d);
        lrow[mi][j] = lrow[mi][j] * alpha[mi][j] + v;
      }
    // rescale O
#pragma unroll
    for (int mi = 0; mi < 2; ++mi)
#pragma unroll
      for (int n2 = 0; n2 < 8; ++n2)
#pragma unroll
        for (int j = 0; j < 4; ++j)
          o[mi][n2][j] *= alpha[mi][j];
    // O += P @ V  (A-frags from LDS, B-frags from transposed V, both k-contiguous)
    bf16x8 pa[2][2];
#pragma unroll
    for (int mi = 0; mi < 2; ++mi)
#pragma unroll
      for (int ks = 0; ks < 2; ++ks)
        pa[mi][ks] = *(const bf16x8*)&pw[(mi * 16 + l15) * 72 + ks * 32 + lg * 8];
#pragma unroll
    for (int n2 = 0; n2 < 8; ++n2) {
      const u16* vr = &vtp[(size_t)(n2 * 16 + l15) * 2048 + kt + lg * 8];
      bf16x8 vf0 = *(const bf16x8*)(vr);
      bf16x8 vf1 = *(const bf16x8*)(vr + 32);
#pragma unroll
      for (int mi = 0; mi < 2; ++mi) {
        o[mi][n2] = mfma16(pa[mi][0], vf0, o[mi][n2]);
        o[mi][n2] = mfma16(pa[mi][1], vf1, o[mi][n2]);
      }
    }
  }
  // epilogue: normalize and store bf16
#pragma unroll
  for (int mi = 0; mi < 2; ++mi)
#pragma unroll
    for (int j = 0; j < 4; ++j) {
      float inv = 1.f / lrow[mi][j];
#pragma unroll
      for (int n2 = 0; n2 < 8; ++n2)
        op[(size_t)(q0 + mi * 16 + lg * 4 + j) * 2048 + n2 * 16 + l15] =
            f2bf(o[mi][n2][j] * inv);
    }
}

// ---------------- launch ----------------
extern "C" void kernel_launch(void* const* d_in, const int* in_sizes, int n_in,
                              void* d_out, int out_size, void* d_ws, size_t ws_size,
                              hipStream_t stream) {
  const float* x    = (const float*)d_in[0];   // [2,2048,2048]
  const float* Wqkv = (const float*)d_in[1];   // [6144,2048]
  const float* Wout = (const float*)d_in[2];   // [2048,2048]
  float* out = (float*)d_out;                  // [2,2048,2048] fp32

  u16* ws = (u16*)d_ws;
  u16* xb    = ws;                 //  8,388,608 elems (reused as aout after gemm1)
  u16* wqkvb = ws + 8388608;       // 12,582,912
  u16* woutb = ws + 20971520;      //  4,194,304
  u16* qkbuf = ws + 25165824;      // 16,777,216  ([B][2048][4096])
  u16* vtbuf = ws + 41943040;      //  8,388,608  ([B*16][128][2048])
  u16* aout  = xb;                 // reuse: xb dead after gemm1
  // total: 50,331,648 u16 = 96 MiB <= ws_size (assumed)

  cvt_bf16<<<2048, 256, 0, stream>>>(x,    xb,    8388608 / 4);
  cvt_bf16<<<2048, 256, 0, stream>>>(Wqkv, wqkvb, 12582912 / 4);
  cvt_bf16<<<1024, 256, 0, stream>>>(Wout, woutb, 4194304 / 4);

  gemm_bt<0><<<dim3(48, 32), 256, 0, stream>>>(xb, wqkvb, (void*)qkbuf, vtbuf,
                                               4096, 6144, 2048);
  attn_fwd<<<dim3(16, 16, 2), 256, 0, stream>>>(qkbuf, vtbuf, aout);
  gemm_bt<1><<<dim3(16, 32), 256, 0, stream>>>(aout, woutb, (void*)out, nullptr,
                                               4096, 2048, 2048);
}